// Round 12
// baseline (37.427 us; speedup 1.0000x reference)
//
#include <hip/hip_runtime.h>

// Problem constants (fixed by the reference's setup_inputs):
//   B=128 batches, S=32768 sequence, P=65536 path steps.
#define NB 128
#define NS 32768
#define NP 65536
#define POS_W 5.0f

constexpr int MASK_WORDS = (NB * NS) / 32;   // 131072 words = 512 KB per mask plane
constexpr int WPB        = NS / 32;          // 1024 mask words per batch (4 KB)
constexpr int LOSS_BLOCKS = 512;             // chunked loss: 2048 float4s per block
constexpr int CHUNK4      = (NB * NS / 4) / LOSS_BLOCKS;  // 2048
constexpr int MWPC        = CHUNK4 / 8;      // 256 mask words per chunk

// ws layout:
//   [0, MASK_WORDS*4)                     : global targets bitmap (tbits)
//   [MASK_WORDS*4, +QPB*MASK_WORDS*4)     : QPB partial gt-mask planes
//   [after planes]                        : per-block loss partials (2 KB)
//
// Journal: no hipMemsetAsync for small regions (R7); no mid-stream
// device-scope __threadfence fan-in (R8: -25us); NO grid.sync cooperative
// fusion (R10: 187us). R12: gt was MLP-limited (4 KB in-flight/CU via VGPR
// loads -> ~3.4 TB/s); global_load_lds DMA staging raises in-flight bytes
// without VGPR cost.

// ---------------------------------------------------------------------------
__device__ __forceinline__ void dma16(const void* g, void* l) {
    __builtin_amdgcn_global_load_lds(
        (const __attribute__((address_space(1))) void*)g,
        (__attribute__((address_space(3))) void*)l,
        16, 0, 0);
}
#define GT_WAIT(N) do { \
    asm volatile("s_waitcnt vmcnt(" #N ")" ::: "memory"); \
    __builtin_amdgcn_sched_barrier(0); } while (0)

// ---------------------------------------------------------------------------
// One-shot: targets (16 MB int32) -> 512 KB bitmap, via per-wave ballot.
__global__ __launch_bounds__(256)
void tbit_kernel(const int* __restrict__ targets, unsigned int* __restrict__ tb) {
    constexpr int NSEG = NB * NS / 64;
    const int lane = threadIdx.x & 63;
    const int wid  = (blockIdx.x * blockDim.x + threadIdx.x) >> 6;
    const int nw   = (gridDim.x * blockDim.x) >> 6;
    for (int s = wid; s < NSEG; s += nw) {
        const unsigned long long m = __ballot(targets[(size_t)s * 64 + lane] != 0);
        if (lane == 0)       tb[s * 2]     = (unsigned int)m;
        else if (lane == 32) tb[s * 2 + 1] = (unsigned int)(m >> 32);
    }
}

// ---------------------------------------------------------------------------
// One block = (batch b, plane q), 512 threads (8 waves). int32 fast path:
// each wave owns 1024 consecutive steps (512 int4s = 8 rounds of 64) and
// DMA-stages them through a private 4 KB LDS double-buffer (2-round halves,
// steady vmcnt(2)). Run-boundary prev-pj: shfl_up within round, carry
// register across rounds (shfl from lane 63), one scalar boundary load per
// wave. Random accesses (tbits gather, gbits set) stay in LDS.
template <int QPB>
__global__ __launch_bounds__(512)
void gt_kernel(const int* __restrict__ pw, const unsigned int* __restrict__ tbits_g,
               unsigned int* __restrict__ pmask) {
    __shared__ unsigned int tbits[WPB];   // 4 KB: targets[b] as bits
    __shared__ unsigned int gbits[WPB];   // 4 KB: this block's gt-bit plane
    __shared__ int4 stage[8][256];        // 32 KB: per-wave DMA double-buffer

    // Layout detect (uniform scalar): int64 -> hi word of last elem == 0.
    const int is64 = (pw[2 * (size_t)NP - 1] == 0);

    const int q    = blockIdx.x;
    const int b    = blockIdx.y;
    const int tid  = threadIdx.x;         // 0..511
    const int lane = tid & 63;
    const int w    = tid >> 6;            // wave 0..7

    tbits[tid]       = tbits_g[(size_t)b * WPB + tid];
    tbits[tid + 512] = tbits_g[(size_t)b * WPB + tid + 512];
    gbits[tid]       = 0u;
    gbits[tid + 512] = 0u;
    __syncthreads();

    constexpr int STEPS = NP / QPB;              // steps per block (8192 @ QPB=8)
    const int    k0    = q * STEPS;              // batch-local base step
    const size_t sbase = (size_t)b * NP + k0;    // global base step
    const int4*  p4    = (const int4*)pw;

    if (!is64) {
        // ---- int32 layout: one int4 = 2 pairs {pi0,pj0,pi1,pj1} ----
        constexpr int WSTEPS = STEPS / 8;        // 1024 steps per wave
        const int    kw    = k0 + w * WSTEPS;    // wave's first step
        const size_t ibase = (sbase >> 1) + (size_t)w * (WSTEPS / 2); // int4 idx

        // Boundary: prev pj for the wave's first step (uniform-address load).
        int carry = -1;
        if (kw != 0) carry = pw[2 * ((size_t)b * NP + kw) - 1];

        // Process 2 rounds (128 int4s) from half h of this wave's buffer.
        auto proc2 = [&](int h) {
            #pragma unroll
            for (int rr = 0; rr < 2; ++rr) {
                const int4 a = stage[w][h * 128 + rr * 64 + lane];
                const int pi0 = a.x, pj0 = a.y, pi1 = a.z, pj1 = a.w;
                const int pl = __shfl_up(pj1, 1);
                const int prev = (lane == 0) ? carry : pl;
                const bool f0 = (pj0 != prev);
                const bool f1 = (pj1 != pj0);
                if (f0 && ((tbits[pj0 >> 5] >> (pj0 & 31)) & 1u))
                    atomicOr(&gbits[pi0 >> 5], 1u << (pi0 & 31));
                if (f1 && ((tbits[pj1 >> 5] >> (pj1 & 31)) & 1u))
                    atomicOr(&gbits[pi1 >> 5], 1u << (pi1 & 31));
                carry = __shfl(pj1, 63);
            }
        };
        // Issue 2 rounds (r, r+1) into half h.
        auto issue2 = [&](int r, int h) {
            dma16(p4 + ibase + (size_t)r * 64 + lane, &stage[w][h * 128]);
            dma16(p4 + ibase + (size_t)(r + 1) * 64 + lane, &stage[w][h * 128 + 64]);
        };

        issue2(0, 0); issue2(2, 1);   // 4 in flight
        GT_WAIT(2);  proc2(0);        // r0,r1 ready; r2,r3 flying
        issue2(4, 0);
        GT_WAIT(2);  proc2(1);        // r2,r3 ready; r4,r5 flying
        issue2(6, 1);
        GT_WAIT(2);  proc2(0);        // r4,r5 ready; r6,r7 flying
        GT_WAIT(0);  proc2(1);        // r6,r7 ready
    } else {
        // ---- int64 layout fallback (VGPR path, R11 form) ----
        constexpr int NIT = STEPS / 512;
        constexpr int NCH = (NIT + 7) / 8;
        const int wbase = tid & ~63;
        int bval = -1;
        if (lane < NIT) {
            const int kf = k0 + lane * 512 + wbase;
            if (kf != 0) bval = pw[4 * ((size_t)b * NP + kf) - 2];
        }
        #pragma unroll
        for (int ch = 0; ch < NCH; ++ch) {
            int4 a[8];
            #pragma unroll
            for (int j = 0; j < 8; ++j) a[j] = p4[sbase + (ch * 8 + j) * 512 + tid];
            #pragma unroll
            for (int j = 0; j < 8; ++j) {
                const int it = ch * 8 + j;
                const int pi = a[j].x, pj = a[j].z;
                const int pl = __shfl_up(pj, 1);
                const int bv = __shfl(bval, it);
                const int prev = (lane == 0) ? bv : pl;
                if ((pj != prev) && ((tbits[pj >> 5] >> (pj & 31)) & 1u))
                    atomicOr(&gbits[pi >> 5], 1u << (pi & 31));
            }
        }
    }
    __syncthreads();

    unsigned int* dst = pmask + (size_t)q * MASK_WORDS + (size_t)b * WPB;
    dst[tid]       = gbits[tid];
    dst[tid + 512] = gbits[tid + 512];
}

// ---------------------------------------------------------------------------
// Chunked streaming loss: each block owns a contiguous 2048-float4 chunk.
// The QPB planes' 256 mask words are OR-merged into LDS once (coalesced),
// then preds stream with LDS-broadcast mask reads. Fence-free partials.
template <int QPB>
__global__ __launch_bounds__(256)
void loss_kernel(const float* __restrict__ preds, const unsigned int* __restrict__ pmask,
                 float* __restrict__ partials) {
    __shared__ unsigned int mmask[MWPC];  // 1 KB merged mask for this chunk
    const int tid = threadIdx.x;
    const int cb4 = blockIdx.x * CHUNK4;  // chunk base (float4 units)
    const int mb  = blockIdx.x * MWPC;    // chunk base (mask words)

    unsigned int mw = 0u;
    #pragma unroll
    for (int q = 0; q < QPB; ++q)
        mw |= pmask[(size_t)q * MASK_WORDS + mb + tid];
    mmask[tid] = mw;
    __syncthreads();

    float acc = 0.f;
    #pragma unroll
    for (int it = 0; it < CHUNK4 / 256; ++it) {
        const int li = it * 256 + tid;    // local float4 index
        const float4 x = reinterpret_cast<const float4*>(preds)[cb4 + li];
        const unsigned int m = mmask[li >> 3] >> ((li & 7) * 4);
        const float xs[4] = {x.x, x.y, x.z, x.w};
        #pragma unroll
        for (int j = 0; j < 4; ++j) {
            const float v = xs[j];
            // stable softplus: sp(v)=log(1+exp(-|v|))+max(v,0); sp(-v)=sp(v)-v
            const float t = __logf(1.f + __expf(-fabsf(v)));
            const float sp_pos = t + fmaxf(v, 0.f);
            const float sp_neg = sp_pos - v;
            acc += ((m >> j) & 1u) ? POS_W * sp_neg : sp_pos;
        }
    }
    for (int off = 32; off; off >>= 1) acc += __shfl_down(acc, off);
    __shared__ float sacc[4];
    const int wave = tid >> 6, lane = tid & 63;
    if (lane == 0) sacc[wave] = acc;
    __syncthreads();
    if (tid == 0) {
        float s = 0.f;
        #pragma unroll
        for (int w = 0; w < 4; ++w) s += sacc[w];
        partials[blockIdx.x] = s;
    }
}

// ---------------------------------------------------------------------------
__global__ __launch_bounds__(256)
void final_kernel(const float* __restrict__ partials, float* __restrict__ out) {
    float acc = 0.f;
    for (int i = threadIdx.x; i < LOSS_BLOCKS; i += 256) acc += partials[i];
    for (int off = 32; off; off >>= 1) acc += __shfl_down(acc, off);
    __shared__ float sacc[4];
    const int wave = threadIdx.x >> 6, lane = threadIdx.x & 63;
    if (lane == 0) sacc[wave] = acc;
    __syncthreads();
    if (threadIdx.x == 0) {
        float s = 0.f;
        #pragma unroll
        for (int w = 0; w < 4; ++w) s += sacc[w];
        out[0] = s * (1.0f / ((float)NB * (float)NS));
    }
}

// ---------------------------------------------------------------------------
extern "C" void kernel_launch(void* const* d_in, const int* in_sizes, int n_in,
                              void* d_out, int out_size, void* d_ws, size_t ws_size,
                              hipStream_t stream) {
    const float* preds   = (const float*)d_in[0];
    const int*   targets = (const int*)d_in[1];
    const int*   paths_w = (const int*)d_in[2];   // int32 words; layout auto-detected
    float*       out     = (float*)d_out;

    // Pick planes-per-batch by available workspace (deterministic for fixed ws).
    int qpb = 8;
    while (qpb > 2 &&
           ws_size < (size_t)(1 + qpb) * MASK_WORDS * 4 + (size_t)LOSS_BLOCKS * 4)
        qpb >>= 1;

    unsigned int* tbits_g  = (unsigned int*)d_ws;
    unsigned int* pmask    = tbits_g + MASK_WORDS;
    float*        partials = (float*)((char*)d_ws +
                              (size_t)(1 + qpb) * MASK_WORDS * 4);

    tbit_kernel<<<1024, 256, 0, stream>>>(targets, tbits_g);

    dim3 g1(qpb, NB);
    switch (qpb) {
        case 8:
            gt_kernel<8><<<g1, 512, 0, stream>>>(paths_w, tbits_g, pmask);
            loss_kernel<8><<<LOSS_BLOCKS, 256, 0, stream>>>(preds, pmask, partials);
            break;
        case 4:
            gt_kernel<4><<<g1, 512, 0, stream>>>(paths_w, tbits_g, pmask);
            loss_kernel<4><<<LOSS_BLOCKS, 256, 0, stream>>>(preds, pmask, partials);
            break;
        default:
            gt_kernel<2><<<g1, 512, 0, stream>>>(paths_w, tbits_g, pmask);
            loss_kernel<2><<<LOSS_BLOCKS, 256, 0, stream>>>(preds, pmask, partials);
            break;
    }

    final_kernel<<<1, 256, 0, stream>>>(partials, out);
}

// Round 13
// 36.747 us; speedup vs baseline: 1.0185x; 1.0185x over previous
//
#include <hip/hip_runtime.h>

// Problem constants (fixed by the reference's setup_inputs):
//   B=128 batches, S=32768 sequence, P=65536 path steps.
#define NB 128
#define NS 32768
#define NP 65536
#define POS_W 5.0f

constexpr int MASK_WORDS = (NB * NS) / 32;   // 131072 words = 512 KB per mask plane
constexpr int WPB        = NS / 32;          // 1024 mask words per batch (4 KB)
constexpr int QPB        = 4;                // planes per batch (fixed)
constexpr int LOSS_BLOCKS = 512;             // chunked loss: 2048 float4s per block
constexpr int CHUNK4      = (NB * NS / 4) / LOSS_BLOCKS;  // 2048
constexpr int MWPC        = CHUNK4 / 8;      // 256 mask words per chunk

// ws layout:
//   [0, MASK_WORDS*4)                     : global targets bitmap (tbits)
//   [MASK_WORDS*4, +QPB*MASK_WORDS*4)     : QPB partial gt-mask planes
//   [after planes]                        : per-block loss partials (2 KB)
//
// Journal: no hipMemsetAsync for small regions (R7); no mid-stream
// device-scope __threadfence fan-in (R8: -25us); NO grid.sync cooperative
// fusion (R10: 187us). R12: LDS-DMA staging + serial carry chain regressed
// (-4us) -- keep iterations INDEPENDENT (precomputed per-iteration boundary
// values) and keep bulk path data out of the DS pipe. R13: pipelined register
// chunks (issue ch N+2 while processing ch N) to force real MLP.

// ---------------------------------------------------------------------------
// One-shot: targets (16 MB int32) -> 512 KB bitmap, via per-wave ballot.
__global__ __launch_bounds__(256)
void tbit_kernel(const int* __restrict__ targets, unsigned int* __restrict__ tb) {
    constexpr int NSEG = NB * NS / 64;
    const int lane = threadIdx.x & 63;
    const int wid  = (blockIdx.x * blockDim.x + threadIdx.x) >> 6;
    const int nw   = (gridDim.x * blockDim.x) >> 6;
    for (int s = wid; s < NSEG; s += nw) {
        const unsigned long long m = __ballot(targets[(size_t)s * 64 + lane] != 0);
        if (lane == 0)       tb[s * 2]     = (unsigned int)m;
        else if (lane == 32) tb[s * 2 + 1] = (unsigned int)(m >> 32);
    }
}

// ---------------------------------------------------------------------------
// One block = (batch b, plane q), 256 threads (4 waves). Each block covers
// 16384 consecutive steps; per thread 32 int4s in 4 chunks of 8, processed
// with a rolling register double-buffer (chunk N+1..N+2 in flight while N is
// consumed). Run boundaries via per-iteration PRECOMPUTED bvals (lanes hold
// them; iterations stay independent -- no serial carry, R12 lesson).
// Random accesses (tbits gather, gbits set) stay in LDS.
__global__ __launch_bounds__(256)
void gt_kernel(const int* __restrict__ pw, const unsigned int* __restrict__ tbits_g,
               unsigned int* __restrict__ pmask) {
    __shared__ unsigned int tbits[WPB];   // 4 KB: targets[b] as bits
    __shared__ unsigned int gbits[WPB];   // 4 KB: this block's gt-bit plane

    // Layout detect (uniform scalar): int64 -> hi word of last elem == 0.
    const int is64 = (pw[2 * (size_t)NP - 1] == 0);

    const int q    = blockIdx.x;          // plane 0..QPB-1
    const int b    = blockIdx.y;          // batch
    const int tid  = threadIdx.x;         // 0..255
    const int lane = tid & 63;
    const int wbase = tid & ~63;

    #pragma unroll
    for (int r = 0; r < 4; ++r) {
        tbits[r * 256 + tid] = tbits_g[(size_t)b * WPB + r * 256 + tid];
        gbits[r * 256 + tid] = 0u;
    }
    __syncthreads();

    constexpr int STEPS = NP / QPB;              // 16384 steps per block
    const int    k0    = q * STEPS;              // batch-local base step
    const size_t sbase = (size_t)b * NP + k0;    // global base step
    const int4*  p4    = (const int4*)pw;

    if (!is64) {
        // ---- int32 layout: one int4 = 2 pairs {pi0,pj0,pi1,pj1} ----
        constexpr int NIT = STEPS / (256 * 2);   // 32 iterations per thread
        const size_t pb = sbase >> 1;            // int4 base index

        // Per-(wave,iteration) boundary: lane l holds prev-pj for iter l.
        int bval = -1;
        if (lane < NIT) {
            const int kf = k0 + (lane * 256 + wbase) * 2;
            if (kf != 0) bval = pw[2 * ((size_t)b * NP + kf) - 1];
        }

        int4 a0[8], a1[8];
        #define GT_ISSUE(buf, ch) \
            _Pragma("unroll") \
            for (int j = 0; j < 8; ++j) buf[j] = p4[pb + ((ch) * 8 + j) * 256 + tid];
        #define GT_PROC(buf, ch) \
            _Pragma("unroll") \
            for (int j = 0; j < 8; ++j) { \
                const int it = (ch) * 8 + j; \
                const int pi0 = buf[j].x, pj0 = buf[j].y; \
                const int pi1 = buf[j].z, pj1 = buf[j].w; \
                const int pl = __shfl_up(pj1, 1); \
                const int bv = __shfl(bval, it); \
                const int prev = (lane == 0) ? bv : pl; \
                const bool f0 = (pj0 != prev); \
                const bool f1 = (pj1 != pj0); \
                if (f0 && ((tbits[pj0 >> 5] >> (pj0 & 31)) & 1u)) \
                    atomicOr(&gbits[pi0 >> 5], 1u << (pi0 & 31)); \
                if (f1 && ((tbits[pj1 >> 5] >> (pj1 & 31)) & 1u)) \
                    atomicOr(&gbits[pi1 >> 5], 1u << (pi1 & 31)); \
            }

        GT_ISSUE(a0, 0)
        GT_ISSUE(a1, 1)
        GT_PROC(a0, 0)
        GT_ISSUE(a0, 2)
        GT_PROC(a1, 1)
        GT_ISSUE(a1, 3)
        GT_PROC(a0, 2)
        GT_PROC(a1, 3)
        #undef GT_ISSUE
        #undef GT_PROC
    } else {
        // ---- int64 layout: one int4 = 1 pair (pi=x, pj=z) ----
        constexpr int NIT = STEPS / 256;         // 64 iterations per thread
        int bval = -1;
        {
            const int kf = k0 + lane * 256 + wbase;   // lane == iteration
            if (kf != 0) bval = pw[4 * ((size_t)b * NP + kf) - 2];
        }

        int4 a0[8], a1[8];
        #define GT_ISSUE64(buf, ch) \
            _Pragma("unroll") \
            for (int j = 0; j < 8; ++j) buf[j] = p4[sbase + ((ch) * 8 + j) * 256 + tid];
        #define GT_PROC64(buf, ch) \
            _Pragma("unroll") \
            for (int j = 0; j < 8; ++j) { \
                const int it = (ch) * 8 + j; \
                const int pi = buf[j].x, pj = buf[j].z; \
                const int pl = __shfl_up(pj, 1); \
                const int bv = __shfl(bval, it); \
                const int prev = (lane == 0) ? bv : pl; \
                if ((pj != prev) && ((tbits[pj >> 5] >> (pj & 31)) & 1u)) \
                    atomicOr(&gbits[pi >> 5], 1u << (pi & 31)); \
            }

        GT_ISSUE64(a0, 0)
        GT_ISSUE64(a1, 1)
        #pragma unroll
        for (int ch = 0; ch < 8; ch += 2) {
            GT_PROC64(a0, ch)
            if (ch + 2 < 8) GT_ISSUE64(a0, ch + 2)
            GT_PROC64(a1, ch + 1)
            if (ch + 3 < 8) GT_ISSUE64(a1, ch + 3)
        }
        #undef GT_ISSUE64
        #undef GT_PROC64
    }
    __syncthreads();

    unsigned int* dst = pmask + (size_t)q * MASK_WORDS + (size_t)b * WPB;
    #pragma unroll
    for (int r = 0; r < 4; ++r) dst[r * 256 + tid] = gbits[r * 256 + tid];
}

// ---------------------------------------------------------------------------
// Chunked streaming loss: each block owns a contiguous 2048-float4 chunk.
// The QPB planes' 256 mask words are OR-merged into LDS once (coalesced),
// then preds stream with LDS-broadcast mask reads. Fence-free partials.
__global__ __launch_bounds__(256)
void loss_kernel(const float* __restrict__ preds, const unsigned int* __restrict__ pmask,
                 float* __restrict__ partials) {
    __shared__ unsigned int mmask[MWPC];  // 1 KB merged mask for this chunk
    const int tid = threadIdx.x;
    const int cb4 = blockIdx.x * CHUNK4;  // chunk base (float4 units)
    const int mb  = blockIdx.x * MWPC;    // chunk base (mask words)

    unsigned int mw = 0u;
    #pragma unroll
    for (int q = 0; q < QPB; ++q)
        mw |= pmask[(size_t)q * MASK_WORDS + mb + tid];
    mmask[tid] = mw;
    __syncthreads();

    float acc = 0.f;
    #pragma unroll
    for (int it = 0; it < CHUNK4 / 256; ++it) {
        const int li = it * 256 + tid;    // local float4 index
        const float4 x = reinterpret_cast<const float4*>(preds)[cb4 + li];
        const unsigned int m = mmask[li >> 3] >> ((li & 7) * 4);
        const float xs[4] = {x.x, x.y, x.z, x.w};
        #pragma unroll
        for (int j = 0; j < 4; ++j) {
            const float v = xs[j];
            // stable softplus: sp(v)=log(1+exp(-|v|))+max(v,0); sp(-v)=sp(v)-v
            const float t = __logf(1.f + __expf(-fabsf(v)));
            const float sp_pos = t + fmaxf(v, 0.f);
            const float sp_neg = sp_pos - v;
            acc += ((m >> j) & 1u) ? POS_W * sp_neg : sp_pos;
        }
    }
    for (int off = 32; off; off >>= 1) acc += __shfl_down(acc, off);
    __shared__ float sacc[4];
    const int wave = tid >> 6, lane = tid & 63;
    if (lane == 0) sacc[wave] = acc;
    __syncthreads();
    if (tid == 0) {
        float s = 0.f;
        #pragma unroll
        for (int w = 0; w < 4; ++w) s += sacc[w];
        partials[blockIdx.x] = s;
    }
}

// ---------------------------------------------------------------------------
__global__ __launch_bounds__(256)
void final_kernel(const float* __restrict__ partials, float* __restrict__ out) {
    float acc = 0.f;
    for (int i = threadIdx.x; i < LOSS_BLOCKS; i += 256) acc += partials[i];
    for (int off = 32; off; off >>= 1) acc += __shfl_down(acc, off);
    __shared__ float sacc[4];
    const int wave = threadIdx.x >> 6, lane = threadIdx.x & 63;
    if (lane == 0) sacc[wave] = acc;
    __syncthreads();
    if (threadIdx.x == 0) {
        float s = 0.f;
        #pragma unroll
        for (int w = 0; w < 4; ++w) s += sacc[w];
        out[0] = s * (1.0f / ((float)NB * (float)NS));
    }
}

// ---------------------------------------------------------------------------
extern "C" void kernel_launch(void* const* d_in, const int* in_sizes, int n_in,
                              void* d_out, int out_size, void* d_ws, size_t ws_size,
                              hipStream_t stream) {
    const float* preds   = (const float*)d_in[0];
    const int*   targets = (const int*)d_in[1];
    const int*   paths_w = (const int*)d_in[2];   // int32 words; layout auto-detected
    float*       out     = (float*)d_out;

    unsigned int* tbits_g  = (unsigned int*)d_ws;
    unsigned int* pmask    = tbits_g + MASK_WORDS;
    float*        partials = (float*)((char*)d_ws +
                              (size_t)(1 + QPB) * MASK_WORDS * 4);

    tbit_kernel<<<1024, 256, 0, stream>>>(targets, tbits_g);

    dim3 g1(QPB, NB);
    gt_kernel<<<g1, 256, 0, stream>>>(paths_w, tbits_g, pmask);

    loss_kernel<<<LOSS_BLOCKS, 256, 0, stream>>>(preds, pmask, partials);
    final_kernel<<<1, 256, 0, stream>>>(partials, out);
}